// Round 5
// baseline (434.835 us; speedup 1.0000x reference)
//
#include <hip/hip_runtime.h>
#include <math.h>

#define T_DIM 8192
#define D_DIM 7168
#define E_DIM 256
#define N_GROUPS 8
#define TOPK_GROUPS 4
#define TOP_K 8

#define N_TOK 64      // tokens per GEMM block
#define BK 32         // k per chunk (one 16x16x32 MFMA k-step)
#define CHUNK_HALVES (E_DIM * BK)   // 8192 halves = 16 KB image per chunk per hi/lo
#define WSCALE 512.0f
#define INV_WSCALE (1.0f / 512.0f)

typedef _Float16 half8 __attribute__((ext_vector_type(8)));
typedef _Float16 half4v __attribute__((ext_vector_type(4)));
typedef float floatx4 __attribute__((ext_vector_type(4)));

// ---------------------------------------------------------------------------
// Kernel 0: split W [D][E] fp32 -> wph/wpl in per-lane FRAGMENT order:
// the half for (k = c*32 + g*8 + j, expert e) lives at halves-offset
//   ((c*4 + g)*256 + e)*8 + j
// so a GEMM lane (lm,kq) fetches its whole 8-half A-fragment for tile mt
// with ONE global_load_dwordx4. 16 lanes read 256 contiguous bytes per
// granule row -> fully coalesced; L2/L3 serve the cross-block reuse.
// ---------------------------------------------------------------------------
__global__ __launch_bounds__(256) void wprep_kernel(
    const float* __restrict__ w, _Float16* __restrict__ wph, _Float16* __restrict__ wpl)
{
    __shared__ float tile[64][65];
    const int k0 = blockIdx.x * 64, e0 = blockIdx.y * 64;
    const int tid = threadIdx.x;
    {
        const int kk = tid >> 4, e4 = (tid & 15) * 4;
#pragma unroll
        for (int i = 0; i < 4; i++) {
            const float4 v = *(const float4*)(w + (size_t)(k0 + kk + i * 16) * E_DIM + e0 + e4);
            tile[kk + i * 16][e4 + 0] = v.x;
            tile[kk + i * 16][e4 + 1] = v.y;
            tile[kk + i * 16][e4 + 2] = v.z;
            tile[kk + i * 16][e4 + 3] = v.w;
        }
    }
    __syncthreads();
    {
        const int ee = tid >> 4, kk4 = (tid & 15) * 4;
        const int c_in = (k0 + kk4) >> 5;       // global chunk index
        const int g = (kk4 >> 3) & 3;           // granule within chunk
        const int j0 = kk4 & 7;                 // 0 or 4
#pragma unroll
        for (int i = 0; i < 4; i++) {
            const int el = ee + i * 16;
            const int e = e0 + el;
            half4v hh, ll;
#pragma unroll
            for (int j = 0; j < 4; j++) {
                const float v = tile[kk4 + j][el] * WSCALE;
                const _Float16 h = (_Float16)v;
                hh[j] = h;
                ll[j] = (_Float16)(v - (float)h);
            }
            const size_t off = ((size_t)(c_in * 4 + g) * E_DIM + e) * 8 + j0;
            *(half4v*)(wph + off) = hh;
            *(half4v*)(wpl + off) = ll;
        }
    }
}

// ---------------------------------------------------------------------------
// Kernel 1: split-fp16 MFMA GEMM -- NO LDS, NO BARRIERS. Each of the 4 waves
// in a block is a fully independent MFMA stream over its 64-expert slice:
// A fragments global->VGPR (double-buffered E/O, prefetched 1 chunk ahead
// from the fragment-ordered image), B fragments global->VGPR (each lane's
// 8 token-row floats = two float4, prefetched 1 chunk ahead, cvt after
// compute). Waves drift freely; latency is hidden by prefetch distance +
// 2 waves/SIMD; no lockstep straggler stalls. Chunk order and MFMA sequence
// identical to prior rounds -> bitwise-identical accumulation.
// ---------------------------------------------------------------------------
__device__ __forceinline__ void cvt_split8(const float4 v0, const float4 v1,
                                           half8& h, half8& l)
{
    float f[8] = {v0.x, v0.y, v0.z, v0.w, v1.x, v1.y, v1.z, v1.w};
#pragma unroll
    for (int j = 0; j < 8; j++) {
        const _Float16 hh = (_Float16)f[j];
        h[j] = hh;
        l[j] = (_Float16)(f[j] - (float)hh);
    }
}

// load 4 hi + 4 lo A-fragments for chunk ci into named register buffers
#define LOAD_A(ci, AH, AL)                                                    \
    do {                                                                      \
        const char* ah_ = aHbase + (size_t)(ci) * (CHUNK_HALVES * 2);         \
        const char* al_ = aLbase + (size_t)(ci) * (CHUNK_HALVES * 2);         \
        _Pragma("unroll")                                                     \
        for (int mt_ = 0; mt_ < 4; mt_++) {                                   \
            AH[mt_] = *(const half8*)(ah_ + mt_ * 256);                       \
            AL[mt_] = *(const half8*)(al_ + mt_ * 256);                       \
        }                                                                     \
    } while (0)

// fallback: build A fragments from raw w[k][e] (bitwise-same split values)
#define LOAD_A_CONV(kc_, AH, AL)                                              \
    do {                                                                      \
        _Pragma("unroll")                                                     \
        for (int mt_ = 0; mt_ < 4; mt_++) {                                   \
            const int e_ = we0 + mt_ * 16 + lm;                               \
            _Pragma("unroll")                                                 \
            for (int jj_ = 0; jj_ < 8; jj_++) {                               \
                const float v_ =                                              \
                    wraw[(size_t)((kc_) + kq * 8 + jj_) * E_DIM + e_] * WSCALE; \
                const _Float16 h_ = (_Float16)v_;                             \
                AH[mt_][jj_] = h_;                                            \
                AL[mt_][jj_] = (_Float16)(v_ - (float)h_);                    \
            }                                                                 \
        }                                                                     \
    } while (0)

// prefetch lane's 4 raw B fragments (8 floats each) for k-offset kc_
#define LOAD_B_RAW(kc_)                                                       \
    do {                                                                      \
        _Pragma("unroll")                                                     \
        for (int nt_ = 0; nt_ < 4; nt_++) {                                   \
            const float* bp_ = xb + (size_t)nt_ * 16 * D_DIM + (kc_);         \
            fB[2 * nt_]     = *(const float4*)(bp_);                          \
            fB[2 * nt_ + 1] = *(const float4*)(bp_ + 4);                      \
        }                                                                     \
    } while (0)

// convert raw floats -> current B fragment registers (single buffer)
#define CVT_B                                                                 \
    do {                                                                      \
        _Pragma("unroll")                                                     \
        for (int nt_ = 0; nt_ < 4; nt_++)                                     \
            cvt_split8(fB[2 * nt_], fB[2 * nt_ + 1], bH[nt_], bL[nt_]);       \
    } while (0)

#define COMPUTE_CHUNK(AH, AL)                                                 \
    do {                                                                      \
        _Pragma("unroll")                                                     \
        for (int nt_ = 0; nt_ < 4; nt_++) {                                   \
            const half8 bh = bH[nt_];                                         \
            const half8 bl = bL[nt_];                                         \
            _Pragma("unroll")                                                 \
            for (int mt_ = 0; mt_ < 4; mt_++) {                               \
                acc[mt_][nt_] = __builtin_amdgcn_mfma_f32_16x16x32_f16(AH[mt_], bh, acc[mt_][nt_], 0, 0, 0); \
                acc[mt_][nt_] = __builtin_amdgcn_mfma_f32_16x16x32_f16(AH[mt_], bl, acc[mt_][nt_], 0, 0, 0); \
                acc[mt_][nt_] = __builtin_amdgcn_mfma_f32_16x16x32_f16(AL[mt_], bh, acc[mt_][nt_], 0, 0, 0); \
            }                                                                 \
        }                                                                     \
    } while (0)

// chunk body: prefetch chunk i+1 (A->named regs, B->raw floats), compute
// chunk i, then cvt B(i+1) into the (now free) current B registers.
#define CHUNK_BODY(i_, AHc, ALc, AHn, ALn)                                    \
    do {                                                                      \
        const int kn_ = k0 + ((i_) + 1) * BK;                                 \
        if constexpr (CONVW) { LOAD_A_CONV(kn_, AHn, ALn); }                  \
        else                 { LOAD_A(cbase + (i_) + 1, AHn, ALn); }          \
        LOAD_B_RAW(kn_);                                                      \
        COMPUTE_CHUNK(AHc, ALc);                                              \
        CVT_B;                                                                \
    } while (0)

template <bool CONVW>
__global__ __launch_bounds__(256, 2) void gemm_split_kernel(
    const float* __restrict__ x, const _Float16* __restrict__ wph,
    const _Float16* __restrict__ wpl, const float* __restrict__ wraw,
    float* __restrict__ partial, int kslen)
{
    const int s = blockIdx.x, m = blockIdx.y;
    const int tid = threadIdx.x;
    const int k0 = s * kslen;
    const size_t t0 = (size_t)m * N_TOK;

    const int wave = tid >> 6, lane = tid & 63;
    const int lm = lane & 15, kq = lane >> 4; // fragment row / k-granule
    const int we0 = wave * 64;                // wave's expert base (4 waves x 64e)

    // per-lane A fragment base pointers (chunk-image fragment order)
    const int cbase = k0 / BK;
    const int laneAoff = (kq * E_DIM + we0 + lm) * 16; // bytes within chunk image
    const char* aHbase = (const char*)wph + laneAoff;
    const char* aLbase = (const char*)wpl + laneAoff;

    // per-lane B base: token row t0+lm, k-granule kq (frag nt -> +nt*16 rows)
    const float* xb = x + (t0 + lm) * (size_t)D_DIM + kq * 8;

    floatx4 acc[4][4];
#pragma unroll
    for (int mt = 0; mt < 4; mt++)
#pragma unroll
        for (int nt = 0; nt < 4; nt++) acc[mt][nt] = (floatx4)0.0f;

    const int nch = kslen / BK;   // 56 at KS=4 (always even)

    half8 aHE[4], aLE[4], aHO[4], aLO[4];
    half8 bH[4], bL[4];
    float4 fB[8];

    // ---- prologue: A(0)->E regs, B(0)->regs ----
    if constexpr (CONVW) { LOAD_A_CONV(k0, aHE, aLE); }
    else                 { LOAD_A(cbase, aHE, aLE); }
    LOAD_B_RAW(k0);
    CVT_B;

    // ---- main loop: statically unrolled x2 (named E/O A-buffers) ----
    for (int i = 0; i < nch - 2; i += 2) {
        CHUNK_BODY(i,     aHE, aLE, aHO, aLO);
        CHUNK_BODY(i + 1, aHO, aLO, aHE, aLE);
    }
    // chunk nch-2 (even parity), prefetches nch-1
    CHUNK_BODY(nch - 2, aHE, aLE, aHO, aLO);
    // chunk nch-1: compute only (bH/bL already hold chunk nch-1)
    COMPUTE_CHUNK(aHO, aLO);

    // ---- epilogue: store raw z' partials. C/D: col(token)=lane&15, row(e)=(lane>>4)*4+r
    float* pout = partial + (size_t)s * T_DIM * E_DIM;
    const int rq = lane >> 4;
#pragma unroll
    for (int nt = 0; nt < 4; nt++) {
        const size_t t = t0 + nt * 16 + lm;
#pragma unroll
        for (int mt = 0; mt < 4; mt++) {
            const int e = we0 + mt * 16 + rq * 4;
            *(floatx4*)(pout + t * E_DIM + e) = acc[mt][nt];
        }
    }
}

// ---------------------------------------------------------------------------
// Kernel 2: per-token routing. One wave per token, no barriers.
// Sums KS partials, z = sum * (1/512), score = sigmoid(z).
// ---------------------------------------------------------------------------
__global__ __launch_bounds__(64) void router_kernel(
    const float* __restrict__ partial, const float* __restrict__ bias,
    float* __restrict__ w_out, float* __restrict__ i_out, int ks)
{
    const int t = blockIdx.x;
    const int lane = threadIdx.x;

    __shared__ float sraw[E_DIM];

    float4 zv = make_float4(0.f, 0.f, 0.f, 0.f);
    for (int s = 0; s < ks; s++) {
        const float4 p = *(const float4*)(partial + (size_t)s * T_DIM * E_DIM +
                                          (size_t)t * E_DIM + lane * 4);
        zv.x += p.x; zv.y += p.y; zv.z += p.z; zv.w += p.w;
    }
    float4 sv;
    sv.x = 1.0f / (1.0f + expf(-zv.x * INV_WSCALE));
    sv.y = 1.0f / (1.0f + expf(-zv.y * INV_WSCALE));
    sv.z = 1.0f / (1.0f + expf(-zv.z * INV_WSCALE));
    sv.w = 1.0f / (1.0f + expf(-zv.w * INV_WSCALE));

    const float4 bz = *(const float4*)(bias + lane * 4);
    *(float4*)(&sraw[lane * 4]) = sv; // single wave: no barrier needed

    float sb[4];
    sb[0] = sv.x + bz.x; sb[1] = sv.y + bz.y; sb[2] = sv.z + bz.z; sb[3] = sv.w + bz.w;

    // group top-2 sum (8 lanes per group)
    float m1 = -INFINITY, m2 = -INFINITY;
#pragma unroll
    for (int j = 0; j < 4; j++) {
        const float v = sb[j];
        if (v > m1) { m2 = m1; m1 = v; }
        else if (v > m2) { m2 = v; }
    }
#pragma unroll
    for (int d = 1; d < 8; d <<= 1) {
        const float o1 = __shfl_xor(m1, d);
        const float o2 = __shfl_xor(m2, d);
        const float hi = fmaxf(m1, o1);
        const float lo = fminf(m1, o1);
        m2 = fmaxf(lo, fmaxf(m2, o2));
        m1 = hi;
    }
    const float gscore = m1 + m2;

    float gs[N_GROUPS];
#pragma unroll
    for (int g = 0; g < N_GROUPS; g++) gs[g] = __shfl(gscore, g * 8);

    unsigned gmask = 0u;
#pragma unroll
    for (int r = 0; r < TOPK_GROUPS; r++) {
        int best = 0; float bv = -INFINITY;
#pragma unroll
        for (int g = 0; g < N_GROUPS; g++) {
            const bool taken = (gmask >> g) & 1u;
            if (!taken && gs[g] > bv) { bv = gs[g]; best = g; }
        }
        gmask |= (1u << best);
    }

    const int myg = lane >> 3;
    const float keep = ((gmask >> myg) & 1u) ? 1.0f : 0.0f;
    float v[4];
#pragma unroll
    for (int j = 0; j < 4; j++) v[j] = keep * sb[j];

    int selIdx[TOP_K];
#pragma unroll
    for (int it = 0; it < TOP_K; it++) {
        float bv = -INFINITY; int bi = E_DIM;
#pragma unroll
        for (int j = 0; j < 4; j++) {
            if (v[j] > bv) { bv = v[j]; bi = 4 * lane + j; }
        }
#pragma unroll
        for (int off = 32; off > 0; off >>= 1) {
            const float ov = __shfl_down(bv, off);
            const int   oi = __shfl_down(bi, off);
            if (ov > bv || (ov == bv && oi < bi)) { bv = ov; bi = oi; }
        }
        bi = __shfl(bi, 0);
        selIdx[it] = bi;
        if (lane == (bi >> 2)) v[bi & 3] = -INFINITY;
    }

    float wv[TOP_K];
    float wsum = 0.0f;
#pragma unroll
    for (int it = 0; it < TOP_K; it++) {
        wv[it] = sraw[selIdx[it]];
        wsum += wv[it];
    }
    const float inv = 2.5f / (wsum + 1e-20f);

#pragma unroll
    for (int it = 0; it < TOP_K; it++) {
        if (lane == it) {
            w_out[(size_t)t * TOP_K + it] = wv[it] * inv;
            i_out[(size_t)t * TOP_K + it] = (float)selIdx[it];
        }
    }
}

// ---------------------------------------------------------------------------
extern "C" void kernel_launch(void* const* d_in, const int* in_sizes, int n_in,
                              void* d_out, int out_size, void* d_ws, size_t ws_size,
                              hipStream_t stream) {
    const float* x    = (const float*)d_in[0];
    const float* w    = (const float*)d_in[1];
    const float* bias = (const float*)d_in[2];

    float* w_out = (float*)d_out;
    float* i_out = w_out + (size_t)T_DIM * TOP_K;

    const size_t PART = (size_t)T_DIM * E_DIM * sizeof(float); // 8.39 MB
    const size_t WT   = (size_t)E_DIM * D_DIM * sizeof(_Float16); // 3.67 MB

    int KS; bool convw;
    if      (ws_size >= 4 * PART + 2 * WT) { KS = 4; convw = false; }
    else if (ws_size >= 2 * PART + 2 * WT) { KS = 2; convw = false; }
    else if (ws_size >= 1 * PART + 2 * WT) { KS = 1; convw = false; }
    else                                   { KS = 1; convw = true;  }

    float* partial = (float*)d_ws;
    _Float16* wph = (_Float16*)((char*)d_ws + (size_t)KS * PART);
    _Float16* wpl = wph + (size_t)E_DIM * D_DIM;

    const int kslen = D_DIM / KS;

    if (!convw) {
        wprep_kernel<<<dim3(D_DIM / 64, E_DIM / 64), 256, 0, stream>>>(w, wph, wpl);
        gemm_split_kernel<false><<<dim3(KS, T_DIM / N_TOK), 256, 0, stream>>>(
            x, wph, wpl, w, partial, kslen);
    } else {
        gemm_split_kernel<true><<<dim3(KS, T_DIM / N_TOK), 256, 0, stream>>>(
            x, wph, wpl, w, partial, kslen);
    }
    router_kernel<<<T_DIM, 64, 0, stream>>>(partial, bias, w_out, i_out, KS);
}

// Round 6
// 386.502 us; speedup vs baseline: 1.1251x; 1.1251x over previous
//
#include <hip/hip_runtime.h>
#include <math.h>

#define T_DIM 8192
#define D_DIM 7168
#define E_DIM 256
#define N_GROUPS 8
#define TOPK_GROUPS 4
#define TOP_K 8

#define N_TOK 64      // tokens per GEMM block
#define BK 32         // k per chunk (one 16x16x32 MFMA k-step)
#define CHUNK_HALVES (E_DIM * BK)   // 8192 halves = 16 KB image per chunk per hi/lo
#define WSCALE 512.0f
#define INV_WSCALE (1.0f / 512.0f)

typedef _Float16 half8 __attribute__((ext_vector_type(8)));
typedef _Float16 half4v __attribute__((ext_vector_type(4)));
typedef float floatx4 __attribute__((ext_vector_type(4)));

#define WAITLGKM asm volatile("s_waitcnt lgkmcnt(0)" ::: "memory")
#define SCHEDB __builtin_amdgcn_sched_barrier(0)

// ---------------------------------------------------------------------------
// Kernel 0: split W [D][E] fp32 -> wph/wpl in per-lane FRAGMENT order:
// the half for (k = c*32 + g*8 + j, expert e) lives at halves-offset
//   ((c*4 + g)*256 + e)*8 + j
// so a GEMM lane (lm,kq) fetches its whole 8-half A-fragment for tile mt
// with ONE global_load_dwordx4. 16 lanes read 256 contiguous bytes per
// granule row -> fully coalesced; L2/L3 serve the cross-block reuse.
// ---------------------------------------------------------------------------
__global__ __launch_bounds__(256) void wprep_kernel(
    const float* __restrict__ w, _Float16* __restrict__ wph, _Float16* __restrict__ wpl)
{
    __shared__ float tile[64][65];
    const int k0 = blockIdx.x * 64, e0 = blockIdx.y * 64;
    const int tid = threadIdx.x;
    {
        const int kk = tid >> 4, e4 = (tid & 15) * 4;
#pragma unroll
        for (int i = 0; i < 4; i++) {
            const float4 v = *(const float4*)(w + (size_t)(k0 + kk + i * 16) * E_DIM + e0 + e4);
            tile[kk + i * 16][e4 + 0] = v.x;
            tile[kk + i * 16][e4 + 1] = v.y;
            tile[kk + i * 16][e4 + 2] = v.z;
            tile[kk + i * 16][e4 + 3] = v.w;
        }
    }
    __syncthreads();
    {
        const int ee = tid >> 4, kk4 = (tid & 15) * 4;
        const int c_in = (k0 + kk4) >> 5;       // global chunk index
        const int g = (kk4 >> 3) & 3;           // granule within chunk
        const int j0 = kk4 & 7;                 // 0 or 4
#pragma unroll
        for (int i = 0; i < 4; i++) {
            const int el = ee + i * 16;
            const int e = e0 + el;
            half4v hh, ll;
#pragma unroll
            for (int j = 0; j < 4; j++) {
                const float v = tile[kk4 + j][el] * WSCALE;
                const _Float16 h = (_Float16)v;
                hh[j] = h;
                ll[j] = (_Float16)(v - (float)h);
            }
            const size_t off = ((size_t)(c_in * 4 + g) * E_DIM + e) * 8 + j0;
            *(half4v*)(wph + off) = hh;
            *(half4v*)(wpl + off) = ll;
        }
    }
}

// ---------------------------------------------------------------------------
// Kernel 1: split-fp16 MFMA GEMM. Round-4 structure (A fragments
// global->VGPR direct from the fragment-ordered image, double-buffered E/O,
// prefetched 1 chunk ahead; B (x tile) shared via double-buffered LDS; one
// raw s_barrier + lgkmcnt(0) per chunk, NO vmcnt drain) with the occupancy
// fix: KS=8 -> grid 1024 blocks (4 queued/CU) and __launch_bounds__(256,3)
// -> 3 resident blocks/CU (168 total regs <= 512/3). Occupancy was
// grid-limited at 2 blocks/CU in all prior ~130us variants.
// ---------------------------------------------------------------------------
__device__ __forceinline__ void cvt_split8(const float4 v0, const float4 v1,
                                           half8& h, half8& l)
{
    float f[8] = {v0.x, v0.y, v0.z, v0.w, v1.x, v1.y, v1.z, v1.w};
#pragma unroll
    for (int j = 0; j < 8; j++) {
        const _Float16 hh = (_Float16)f[j];
        h[j] = hh;
        l[j] = (_Float16)(f[j] - (float)hh);
    }
}

// load 4 hi + 4 lo A-fragments for chunk ci into named register buffers
#define LOAD_A(ci, AH, AL)                                                    \
    do {                                                                      \
        const char* ah_ = aHbase + (size_t)(ci) * (CHUNK_HALVES * 2);         \
        const char* al_ = aLbase + (size_t)(ci) * (CHUNK_HALVES * 2);         \
        _Pragma("unroll")                                                     \
        for (int mt_ = 0; mt_ < 4; mt_++) {                                   \
            AH[mt_] = *(const half8*)(ah_ + mt_ * 256);                       \
            AL[mt_] = *(const half8*)(al_ + mt_ * 256);                       \
        }                                                                     \
    } while (0)

// fallback: build A fragments from raw w[k][e] (bitwise-same split values)
#define LOAD_A_CONV(kc_, AH, AL)                                              \
    do {                                                                      \
        _Pragma("unroll")                                                     \
        for (int mt_ = 0; mt_ < 4; mt_++) {                                   \
            const int e_ = we0 + mt_ * 16 + lm;                               \
            _Pragma("unroll")                                                 \
            for (int jj_ = 0; jj_ < 8; jj_++) {                               \
                const float v_ =                                              \
                    wraw[(size_t)((kc_) + kq * 8 + jj_) * E_DIM + e_] * WSCALE; \
                const _Float16 h_ = (_Float16)v_;                             \
                AH[mt_][jj_] = h_;                                            \
                AL[mt_][jj_] = (_Float16)(v_ - (float)h_);                    \
            }                                                                 \
        }                                                                     \
    } while (0)

#define WRITE_B(buf, h_, l_)                                                  \
    do {                                                                      \
        const int boff_ = bt * BK + ((bg ^ ((bt >> 1) & 3)) << 3);            \
        *(half8*)&Bs[buf][0][boff_] = (h_);                                   \
        *(half8*)&Bs[buf][1][boff_] = (l_);                                   \
    } while (0)

#define COMPUTE_CHUNK(AH, AL, bb)                                             \
    do {                                                                      \
        __builtin_amdgcn_s_setprio(1);                                        \
        _Pragma("unroll")                                                     \
        for (int nt_ = 0; nt_ < 4; nt_++) {                                   \
            const int t_ = nt_ * 16 + lm;                                     \
            const int off_ = t_ * BK + ((kq ^ ((t_ >> 1) & 3)) << 3);         \
            const half8 bh = *(const half8*)&Bs[bb][0][off_];                 \
            const half8 bl = *(const half8*)&Bs[bb][1][off_];                 \
            _Pragma("unroll")                                                 \
            for (int mt_ = 0; mt_ < 4; mt_++) {                               \
                acc[mt_][nt_] = __builtin_amdgcn_mfma_f32_16x16x32_f16(AH[mt_], bh, acc[mt_][nt_], 0, 0, 0); \
                acc[mt_][nt_] = __builtin_amdgcn_mfma_f32_16x16x32_f16(AH[mt_], bl, acc[mt_][nt_], 0, 0, 0); \
                acc[mt_][nt_] = __builtin_amdgcn_mfma_f32_16x16x32_f16(AL[mt_], bh, acc[mt_][nt_], 0, 0, 0); \
            }                                                                 \
        }                                                                     \
        __builtin_amdgcn_s_setprio(0);                                        \
    } while (0)

#define BARRIER_PUB                                                            \
    do { WAITLGKM; SCHEDB; __builtin_amdgcn_s_barrier(); SCHEDB; } while (0)

// chunk body: prefetch chunk i+1 (A->regs, x->regs), compute chunk i,
// then cvt+write B(i+1) and publish. pc/pn are compile-time 0/1.
#define CHUNK_BODY(i_, AHc, ALc, AHn, ALn, pc, pn)                            \
    do {                                                                      \
        const int kc_ = k0 + (i_) * BK;                                       \
        const float4 xn0 = *(const float4*)(xrow + kc_ + BK);                 \
        const float4 xn1 = *(const float4*)(xrow + kc_ + BK + 4);             \
        if constexpr (CONVW) { LOAD_A_CONV(kc_ + BK, AHn, ALn); }             \
        else                 { LOAD_A(cbase + (i_) + 1, AHn, ALn); }          \
        COMPUTE_CHUNK(AHc, ALc, pc);                                          \
        {                                                                     \
            half8 h_, l_;                                                     \
            cvt_split8(xn0, xn1, h_, l_);                                     \
            WRITE_B(pn, h_, l_);                                              \
        }                                                                     \
        BARRIER_PUB;                                                          \
    } while (0)

template <bool CONVW>
__global__ __launch_bounds__(256, 3) void gemm_split_kernel(
    const float* __restrict__ x, const _Float16* __restrict__ wph,
    const _Float16* __restrict__ wpl, const float* __restrict__ wraw,
    float* __restrict__ partial, int kslen)
{
    __shared__ _Float16 Bs[2][2][N_TOK * BK]; // [parity][hi/lo] = 16 KB

    const int s = blockIdx.x, m = blockIdx.y;
    const int tid = threadIdx.x;
    const int k0 = s * kslen;
    const size_t t0 = (size_t)m * N_TOK;

    const int wave = tid >> 6, lane = tid & 63;
    const int lm = lane & 15, kq = lane >> 4; // fragment row / k-granule
    const int we0 = wave * 64;                // wave's expert base (4 waves x 64e)

    // B staging map: thread -> (token, k-granule)
    const int bt = tid >> 2;   // 0..63
    const int bg = tid & 3;    // 0..3
    const float* xrow = x + (t0 + bt) * (size_t)D_DIM + bg * 8;

    // per-lane A fragment base pointers (chunk-image fragment order)
    const int cbase = k0 / BK;
    const int laneAoff = (kq * E_DIM + we0 + lm) * 16; // bytes within chunk image
    const char* aHbase = (const char*)wph + laneAoff;
    const char* aLbase = (const char*)wpl + laneAoff;

    floatx4 acc[4][4];
#pragma unroll
    for (int mt = 0; mt < 4; mt++)
#pragma unroll
        for (int nt = 0; nt < 4; nt++) acc[mt][nt] = (floatx4)0.0f;

    const int nch = kslen / BK;   // 28 at KS=8 (always even)

    half8 aHE[4], aLE[4], aHO[4], aLO[4];

    // ---- prologue: A(0)->E regs, x(0)->B[0] ----
    {
        const float4 x0a = *(const float4*)(xrow + k0);
        const float4 x0b = *(const float4*)(xrow + k0 + 4);
        if constexpr (CONVW) { LOAD_A_CONV(k0, aHE, aLE); }
        else                 { LOAD_A(cbase, aHE, aLE); }
        half8 h, l;
        cvt_split8(x0a, x0b, h, l);
        WRITE_B(0, h, l);
        BARRIER_PUB;
    }

    // ---- main loop: statically unrolled x2 (named E/O buffers) ----
    for (int i = 0; i < nch - 2; i += 2) {
        CHUNK_BODY(i,     aHE, aLE, aHO, aLO, 0, 1);
        CHUNK_BODY(i + 1, aHO, aLO, aHE, aLE, 1, 0);
    }
    // chunk nch-2 (even parity), prefetches nch-1
    CHUNK_BODY(nch - 2, aHE, aLE, aHO, aLO, 0, 1);
    // chunk nch-1 (odd parity), compute only
    COMPUTE_CHUNK(aHO, aLO, 1);

    // ---- epilogue: store raw z' partials. C/D: col(token)=lane&15, row(e)=(lane>>4)*4+r
    float* pout = partial + (size_t)s * T_DIM * E_DIM;
    const int rq = lane >> 4;
#pragma unroll
    for (int nt = 0; nt < 4; nt++) {
        const size_t t = t0 + nt * 16 + lm;
#pragma unroll
        for (int mt = 0; mt < 4; mt++) {
            const int e = we0 + mt * 16 + rq * 4;
            *(floatx4*)(pout + t * E_DIM + e) = acc[mt][nt];
        }
    }
}

// ---------------------------------------------------------------------------
// Kernel 2: per-token routing. One wave per token, no barriers.
// Sums KS partials, z = sum * (1/512), score = sigmoid(z).
// ---------------------------------------------------------------------------
__global__ __launch_bounds__(64) void router_kernel(
    const float* __restrict__ partial, const float* __restrict__ bias,
    float* __restrict__ w_out, float* __restrict__ i_out, int ks)
{
    const int t = blockIdx.x;
    const int lane = threadIdx.x;

    __shared__ float sraw[E_DIM];

    float4 zv = make_float4(0.f, 0.f, 0.f, 0.f);
    for (int s = 0; s < ks; s++) {
        const float4 p = *(const float4*)(partial + (size_t)s * T_DIM * E_DIM +
                                          (size_t)t * E_DIM + lane * 4);
        zv.x += p.x; zv.y += p.y; zv.z += p.z; zv.w += p.w;
    }
    float4 sv;
    sv.x = 1.0f / (1.0f + expf(-zv.x * INV_WSCALE));
    sv.y = 1.0f / (1.0f + expf(-zv.y * INV_WSCALE));
    sv.z = 1.0f / (1.0f + expf(-zv.z * INV_WSCALE));
    sv.w = 1.0f / (1.0f + expf(-zv.w * INV_WSCALE));

    const float4 bz = *(const float4*)(bias + lane * 4);
    *(float4*)(&sraw[lane * 4]) = sv; // single wave: no barrier needed

    float sb[4];
    sb[0] = sv.x + bz.x; sb[1] = sv.y + bz.y; sb[2] = sv.z + bz.z; sb[3] = sv.w + bz.w;

    // group top-2 sum (8 lanes per group)
    float m1 = -INFINITY, m2 = -INFINITY;
#pragma unroll
    for (int j = 0; j < 4; j++) {
        const float v = sb[j];
        if (v > m1) { m2 = m1; m1 = v; }
        else if (v > m2) { m2 = v; }
    }
#pragma unroll
    for (int d = 1; d < 8; d <<= 1) {
        const float o1 = __shfl_xor(m1, d);
        const float o2 = __shfl_xor(m2, d);
        const float hi = fmaxf(m1, o1);
        const float lo = fminf(m1, o1);
        m2 = fmaxf(lo, fmaxf(m2, o2));
        m1 = hi;
    }
    const float gscore = m1 + m2;

    float gs[N_GROUPS];
#pragma unroll
    for (int g = 0; g < N_GROUPS; g++) gs[g] = __shfl(gscore, g * 8);

    unsigned gmask = 0u;
#pragma unroll
    for (int r = 0; r < TOPK_GROUPS; r++) {
        int best = 0; float bv = -INFINITY;
#pragma unroll
        for (int g = 0; g < N_GROUPS; g++) {
            const bool taken = (gmask >> g) & 1u;
            if (!taken && gs[g] > bv) { bv = gs[g]; best = g; }
        }
        gmask |= (1u << best);
    }

    const int myg = lane >> 3;
    const float keep = ((gmask >> myg) & 1u) ? 1.0f : 0.0f;
    float v[4];
#pragma unroll
    for (int j = 0; j < 4; j++) v[j] = keep * sb[j];

    int selIdx[TOP_K];
#pragma unroll
    for (int it = 0; it < TOP_K; it++) {
        float bv = -INFINITY; int bi = E_DIM;
#pragma unroll
        for (int j = 0; j < 4; j++) {
            if (v[j] > bv) { bv = v[j]; bi = 4 * lane + j; }
        }
#pragma unroll
        for (int off = 32; off > 0; off >>= 1) {
            const float ov = __shfl_down(bv, off);
            const int   oi = __shfl_down(bi, off);
            if (ov > bv || (ov == bv && oi < bi)) { bv = ov; bi = oi; }
        }
        bi = __shfl(bi, 0);
        selIdx[it] = bi;
        if (lane == (bi >> 2)) v[bi & 3] = -INFINITY;
    }

    float wv[TOP_K];
    float wsum = 0.0f;
#pragma unroll
    for (int it = 0; it < TOP_K; it++) {
        wv[it] = sraw[selIdx[it]];
        wsum += wv[it];
    }
    const float inv = 2.5f / (wsum + 1e-20f);

#pragma unroll
    for (int it = 0; it < TOP_K; it++) {
        if (lane == it) {
            w_out[(size_t)t * TOP_K + it] = wv[it] * inv;
            i_out[(size_t)t * TOP_K + it] = (float)selIdx[it];
        }
    }
}

// ---------------------------------------------------------------------------
extern "C" void kernel_launch(void* const* d_in, const int* in_sizes, int n_in,
                              void* d_out, int out_size, void* d_ws, size_t ws_size,
                              hipStream_t stream) {
    const float* x    = (const float*)d_in[0];
    const float* w    = (const float*)d_in[1];
    const float* bias = (const float*)d_in[2];

    float* w_out = (float*)d_out;
    float* i_out = w_out + (size_t)T_DIM * TOP_K;

    const size_t PART = (size_t)T_DIM * E_DIM * sizeof(float); // 8.39 MB
    const size_t WT   = (size_t)E_DIM * D_DIM * sizeof(_Float16); // 3.67 MB

    int KS; bool convw;
    if      (ws_size >= 8 * PART + 2 * WT) { KS = 8; convw = false; }
    else if (ws_size >= 4 * PART + 2 * WT) { KS = 4; convw = false; }
    else if (ws_size >= 2 * PART + 2 * WT) { KS = 2; convw = false; }
    else if (ws_size >= 1 * PART + 2 * WT) { KS = 1; convw = false; }
    else                                   { KS = 1; convw = true;  }

    float* partial = (float*)d_ws;
    _Float16* wph = (_Float16*)((char*)d_ws + (size_t)KS * PART);
    _Float16* wpl = wph + (size_t)E_DIM * D_DIM;

    const int kslen = D_DIM / KS;

    if (!convw) {
        wprep_kernel<<<dim3(D_DIM / 64, E_DIM / 64), 256, 0, stream>>>(w, wph, wpl);
        gemm_split_kernel<false><<<dim3(KS, T_DIM / N_TOK), 256, 0, stream>>>(
            x, wph, wpl, w, partial, kslen);
    } else {
        gemm_split_kernel<true><<<dim3(KS, T_DIM / N_TOK), 256, 0, stream>>>(
            x, wph, wpl, w, partial, kslen);
    }
    router_kernel<<<T_DIM, 64, 0, stream>>>(partial, bias, w_out, i_out, KS);
}